// Round 6
// baseline (420.473 us; speedup 1.0000x reference)
//
#include <hip/hip_runtime.h>
#include <hip/hip_bf16.h>

#define DIV_UP(a,b) (((a)+(b)-1)/(b))

typedef __attribute__((ext_vector_type(8))) short short8;
typedef __attribute__((ext_vector_type(4))) float floatx4;
typedef _Float16 half2t __attribute__((ext_vector_type(2)));

// ---------- scalar convert helpers ----------
static __device__ __forceinline__ unsigned short f2bf(float v) {
    unsigned u = __builtin_bit_cast(unsigned, v);
    u += 0x7fffu + ((u >> 16) & 1u);
    return (unsigned short)(u >> 16);
}
static __device__ __forceinline__ unsigned short f2h(float v) {
    _Float16 h = (_Float16)v;                  // v_cvt_f16_f32 (RTE)
    return __builtin_bit_cast(unsigned short, h);
}
static __device__ __forceinline__ float fexp2(float x) { return __builtin_amdgcn_exp2f(x); }

static __device__ __forceinline__ half2t mk_h2(float lo, float hi) {
    half2t h; h[0] = (_Float16)lo; h[1] = (_Float16)hi; return h;
}
static __device__ __forceinline__ unsigned ph2(float lo, float hi) {
    return __builtin_bit_cast(unsigned, mk_h2(lo, hi));
}
// v_dot2_f32_f16: 2 f16 MACs per full-rate instr, f32 accumulate
static __device__ __forceinline__ float fdot2h(half2t a, half2t b, float c) {
    return __builtin_amdgcn_fdot2(a, b, c, false);
}
static __device__ __forceinline__ unsigned uget(const uint4 v, int k) {
    return k == 0 ? v.x : k == 1 ? v.y : k == 2 ? v.z : v.w;
}
static __device__ __forceinline__ float h2lo(half2t h) { return (float)h[0]; }
static __device__ __forceinline__ float h2hi(half2t h) { return (float)h[1]; }

// raw per-lane x-row slice type by channels-per-lane
template <int CPL> struct RawT;
template <> struct RawT<8> { using T = uint4; };
template <> struct RawT<4> { using T = uint2; };
template <> struct RawT<2> { using T = unsigned; };

// load CPL f16 channels as CPL/2 packed half2
template <int CPL>
static __device__ __forceinline__ void loadh2(const unsigned short* p, half2t* d) {
    if constexpr (CPL == 8) {
        uint4 v = *(const uint4*)p;
        d[0] = __builtin_bit_cast(half2t, v.x);
        d[1] = __builtin_bit_cast(half2t, v.y);
        d[2] = __builtin_bit_cast(half2t, v.z);
        d[3] = __builtin_bit_cast(half2t, v.w);
    } else if constexpr (CPL == 4) {
        uint2 v = *(const uint2*)p;
        d[0] = __builtin_bit_cast(half2t, v.x);
        d[1] = __builtin_bit_cast(half2t, v.y);
    } else {
        unsigned v = *(const unsigned*)p;
        d[0] = __builtin_bit_cast(half2t, v);
    }
}

template <int CPL>
static __device__ __forceinline__ void store_bf16v(unsigned short* p, const float* s) {
    unsigned short tmp[CPL];
#pragma unroll
    for (int c = 0; c < CPL; ++c) tmp[c] = f2bf(s[c]);
    if constexpr (CPL == 8) *(uint4*)p = *(uint4*)tmp;
    else if constexpr (CPL == 4) *(ushort4*)p = *(ushort4*)tmp;
    else if constexpr (CPL == 2) *(ushort2*)p = *(ushort2*)tmp;
    else p[0] = tmp[0];
}

// ---------- DPP group reduction (VALU pipe, not DS) ----------
template <int CTRL>
static __device__ __forceinline__ float dpp_mv(float x) {
    int r = __builtin_amdgcn_update_dpp(0, __builtin_bit_cast(int, x), CTRL, 0xF, 0xF, false);
    return __builtin_bit_cast(float, r);
}
template <int G>
static __device__ __forceinline__ float group_reduce(float x) {
    x += dpp_mv<0xB1>(x);   // xor 1
    x += dpp_mv<0x4E>(x);   // xor 2
    x += dpp_mv<0x124>(x);  // row_ror:4
    x += dpp_mv<0x128>(x);  // row_ror:8 -> 16-lane sum
    if constexpr (G >= 32) x += __shfl_xor(x, 16, 64);
    if constexpr (G >= 64) x += __shfl_xor(x, 32, 64);
    return x;
}

// ---------- merged weight prep: 3 transposed pairs + x->bf16 ----------
static __device__ __forceinline__ void tr_pair(const float* Wa, const float* Wb, int K, int Nn,
                                               unsigned short* Wt, int i) {
    int tot = K * Nn;
    const float* W = (i < tot) ? Wa : Wb;
    unsigned short* dst = Wt + ((i < tot) ? 0 : (size_t)Nn * K);
    int ii = (i < tot) ? i : i - tot;
    int k = ii % K, n = ii / K;
    dst[(size_t)n * K + k] = f2bf(W[(size_t)k * Nn + n]);
}

__global__ void prep_all(const float* __restrict__ x,
                         const float* __restrict__ Wl1, const float* __restrict__ Wr1,
                         const float* __restrict__ Wl2, const float* __restrict__ Wr2,
                         const float* __restrict__ Wlp, const float* __restrict__ Wrp,
                         unsigned short* __restrict__ xbf,
                         unsigned short* __restrict__ wt1, unsigned short* __restrict__ wt2,
                         unsigned short* __restrict__ wt3, int N) {
    const int S1 = 2 * 64 * 1024, S2 = 2 * 1024 * 256, S3 = 2 * 256 * 384;
    int id = blockIdx.x * blockDim.x + threadIdx.x;
    if (id < S1) tr_pair(Wl1, Wr1, 64, 1024, wt1, id);
    else if (id < S1 + S2) tr_pair(Wl2, Wr2, 1024, 256, wt2, id - S1);
    else if (id < S1 + S2 + S3) tr_pair(Wlp, Wrp, 256, 384, wt3, id - S1 - S2);
    else {
        int i = id - S1 - S2 - S3;
        if (i < N * 64) xbf[i] = f2bf(x[i]);
    }
}

// ---------- MFMA bf16 GEMM with SPLIT f16 output: cols [0,NL)->CL, [NL,2NL)->CR ----------
#define GLOAD_LDS16(gp, lp) \
    __builtin_amdgcn_global_load_lds((const __attribute__((address_space(1))) void*)(gp), \
                                     (__attribute__((address_space(3))) void*)(lp), 16, 0, 0)

__global__ __launch_bounds__(256) void gemm_mfma(
    const unsigned short* __restrict__ A, const unsigned short* __restrict__ Bt,
    unsigned short* __restrict__ CL, unsigned short* __restrict__ CR,
    int M, int NL, int K) {
    __shared__ unsigned short As[128 * 32];
    __shared__ unsigned short Bs[128 * 32];
    const int tid = threadIdx.x;
    const int m0 = blockIdx.y * 128, n0 = blockIdx.x * 128;
    const bool left = (n0 < NL);
    unsigned short* Cb = left ? CL : CR;
    const int nbase = left ? n0 : n0 - NL;
    const int wave = tid >> 6, lane = tid & 63;
    const int wm = (wave >> 1) * 64, wn = (wave & 1) * 64;
    const int r15 = lane & 15, quad = lane >> 4;
    const int srow = lane >> 2, scol = (lane & 3) * 8;
    const int arow0 = m0 + 32 * wave + srow;
    const int brow0 = n0 + 32 * wave + srow;
    const unsigned short* ap0 = A + (size_t)arow0 * K + scol;
    const unsigned short* ap1 = ap0 + (size_t)16 * K;
    const unsigned short* bp0 = Bt + (size_t)brow0 * K + scol;
    const unsigned short* bp1 = bp0 + (size_t)16 * K;
    unsigned short* alds0 = As + (32 * wave) * 32;
    unsigned short* alds1 = alds0 + 16 * 32;
    unsigned short* blds0 = Bs + (32 * wave) * 32;
    unsigned short* blds1 = blds0 + 16 * 32;
    const bool av0 = arow0 < M, av1 = (arow0 + 16) < M;
    floatx4 acc[4][4];
#pragma unroll
    for (int i = 0; i < 4; ++i)
#pragma unroll
        for (int j = 0; j < 4; ++j) acc[i][j] = (floatx4)0.f;

    for (int k0 = 0; k0 < K; k0 += 32) {
        if (av0) GLOAD_LDS16(ap0, alds0);
        if (av1) GLOAD_LDS16(ap1, alds1);
        GLOAD_LDS16(bp0, blds0);
        GLOAD_LDS16(bp1, blds1);
        ap0 += 32; ap1 += 32; bp0 += 32; bp1 += 32;
        __syncthreads();
        short8 af[4], bfr[4];
#pragma unroll
        for (int i = 0; i < 4; ++i)
            af[i] = *(const short8*)(&As[(wm + i * 16 + r15) * 32 + quad * 8]);
#pragma unroll
        for (int j = 0; j < 4; ++j)
            bfr[j] = *(const short8*)(&Bs[(wn + j * 16 + r15) * 32 + quad * 8]);
#pragma unroll
        for (int i = 0; i < 4; ++i)
#pragma unroll
            for (int j = 0; j < 4; ++j)
                acc[i][j] = __builtin_amdgcn_mfma_f32_16x16x32_bf16(af[i], bfr[j], acc[i][j], 0, 0, 0);
        __syncthreads();
    }
#pragma unroll
    for (int i = 0; i < 4; ++i)
#pragma unroll
        for (int j = 0; j < 4; ++j)
#pragma unroll
            for (int r = 0; r < 4; ++r) {
                int m = m0 + wm + i * 16 + quad * 4 + r;
                int n = nbase + wn + j * 16 + r15;
                if (m < M) Cb[(size_t)m * NL + n] = f2h(acc[i][j][r]);   // f16 out
            }
}

// ---------- CSR build for BOTH graphs ----------
__global__ void count2_kernel(const int* __restrict__ dst0, const int* __restrict__ dst1,
                              int E, int N, int* __restrict__ cnt) {
    int e = blockIdx.x * blockDim.x + threadIdx.x;
    if (e < E) atomicAdd(&cnt[dst0[e]], 1);
    else if (e < 2 * E) atomicAdd(&cnt[N + dst1[e - E]], 1);
}

__global__ __launch_bounds__(1024) void scan_kernel(const int* __restrict__ cnt_all, int N,
                                                    int* __restrict__ off_all, int* __restrict__ cur_all) {
    const int* cnt = cnt_all + blockIdx.x * N;
    int* off = off_all + blockIdx.x * (N + 1);
    int* cur = cur_all + blockIdx.x * N;
    __shared__ int part[1024];
    int t = threadIdx.x;
    int per = (N + 1023) >> 10;
    int base = t * per;
    int s = 0;
    for (int i = 0; i < per; ++i) { int idx = base + i; if (idx < N) s += cnt[idx]; }
    part[t] = s;
    __syncthreads();
    for (int d2 = 1; d2 < 1024; d2 <<= 1) {
        int v = (t >= d2) ? part[t - d2] : 0;
        __syncthreads();
        part[t] += v;
        __syncthreads();
    }
    int pre = (t == 0) ? 0 : part[t - 1];
    for (int i = 0; i < per; ++i) {
        int idx = base + i;
        if (idx < N) { off[idx] = pre; cur[idx] = pre; pre += cnt[idx]; }
    }
    if (t == 1023) off[N] = part[1023];
}

__global__ void fill2_kernel(const int* __restrict__ src0, const int* __restrict__ dst0,
                             const int* __restrict__ src1, const int* __restrict__ dst1,
                             int E, int N, int* __restrict__ cur, int2* __restrict__ edges,
                             int* __restrict__ srcs) {
    int e = blockIdx.x * blockDim.x + threadIdx.x;
    if (e < E) {
        int p = atomicAdd(&cur[dst0[e]], 1);
        edges[p] = make_int2(src0[e], e);
        srcs[p] = src0[e];
    } else if (e < 2 * E) {
        int i = e - E;
        int p = atomicAdd(&cur[N + dst1[i]], 1);
        srcs[E + p] = src1[i];
    }
}

// ---------- ea gather into CSR order, duplicated f16 pairs: 32 B/edge ----------
// ead[2j], ead[2j+1]: 8 k-values as (e_k, e_k) half2 — ready-made pk_fma broadcast operand.
__global__ void ea_gather_kernel(const float* __restrict__ ea, const int2* __restrict__ edges,
                                 uint4* __restrict__ ead, int E) {
    int j = blockIdx.x * blockDim.x + threadIdx.x;
    if (j >= E) return;
    int ey = edges[j].y;
    const float4* s = (const float4*)(ea + (size_t)ey * 8);
    float4 a = s[0], b = s[1];
    uint4 o0, o1;
    o0.x = ph2(a.x, a.x); o0.y = ph2(a.y, a.y);
    o0.z = ph2(a.z, a.z); o0.w = ph2(a.w, a.w);
    o1.x = ph2(b.x, b.x); o1.y = ph2(b.y, b.y);
    o1.z = ph2(b.z, b.z); o1.w = ph2(b.w, b.w);
    ead[2 * j]     = o0;
    ead[2 * j + 1] = o1;
}

// ---------- fused attention (HASE): packed-f16 z-pipeline ----------
template <int D, int CPL, int G, int NE>
static __device__ __forceinline__ void hase_group(
    const unsigned short* __restrict__ xl, const uint4* __restrict__ ej,
    const int* __restrict__ sj, const unsigned* wbu,
    const half2t (&att2)[CPL / 2], const half2t (&xr2)[CPL / 2], int c0,
    float& m, float& l, float (&acc)[CPL]) {
    constexpr int P = CPL / 2;
    int src[NE];
#pragma unroll
    for (int n = 0; n < NE; ++n) src[n] = sj[n];
    uint4 ev0[NE], ev1[NE];
#pragma unroll
    for (int n = 0; n < NE; ++n) { ev0[n] = ej[2 * n]; ev1[n] = ej[2 * n + 1]; }
    half2t xv[NE][P], z[NE][P];
#pragma unroll
    for (int n = 0; n < NE; ++n) {
        loadh2<CPL>(xl + (size_t)src[n] * D + c0, xv[n]);
#pragma unroll
        for (int p = 0; p < P; ++p) z[n][p] = xv[n][p] + xr2[p];   // v_pk_add_f16
    }
    // We-matvec: 8 k x P channel-pairs, v_pk_fma_f16 (2 MAC/instr full-rate)
#pragma unroll
    for (int k = 0; k < 8; ++k) {
        half2t wk[P];
        if constexpr (CPL == 8) {
            uint4 w4 = *(const uint4*)(wbu + k * (D / 2));
            wk[0] = __builtin_bit_cast(half2t, w4.x);
            wk[1] = __builtin_bit_cast(half2t, w4.y);
            wk[2] = __builtin_bit_cast(half2t, w4.z);
            wk[3] = __builtin_bit_cast(half2t, w4.w);
        } else {
            uint2 w2 = *(const uint2*)(wbu + k * (D / 2));
            wk[0] = __builtin_bit_cast(half2t, w2.x);
            wk[1] = __builtin_bit_cast(half2t, w2.y);
        }
#pragma unroll
        for (int n = 0; n < NE; ++n) {
            unsigned eu = (k < 4) ? uget(ev0[n], k) : uget(ev1[n], k - 4);
            half2t e2 = __builtin_bit_cast(half2t, eu);
#pragma unroll
            for (int p = 0; p < P; ++p)
                z[n][p] = __builtin_elementwise_fma(e2, wk[p], z[n][p]);
        }
    }
    const half2t c02 = mk_h2(0.2f, 0.2f);
    float lg[NE];
#pragma unroll
    for (int n = 0; n < NE; ++n) {
        float t = 0.f;
#pragma unroll
        for (int p = 0; p < P; ++p) {
            half2t zz = z[n][p];
            half2t lz = __builtin_elementwise_max(zz, zz * c02);   // pk_mul + pk_max
            t = fdot2h(att2[p], lz, t);
        }
        lg[n] = group_reduce<G>(t);
    }
    float mn = m;
#pragma unroll
    for (int n = 0; n < NE; ++n) mn = fmaxf(mn, lg[n]);
    float sc = fexp2(m - mn);
    float pr[NE], ps = 0.f;
#pragma unroll
    for (int n = 0; n < NE; ++n) { pr[n] = fexp2(lg[n] - mn); ps += pr[n]; }
    m = mn;
    l = fmaf(l, sc, ps);
#pragma unroll
    for (int p = 0; p < P; ++p) {
        float t0 = pr[0] * h2lo(xv[0][p]);
        float t1 = pr[0] * h2hi(xv[0][p]);
#pragma unroll
        for (int n = 1; n < NE; ++n) {
            t0 = fmaf(pr[n], h2lo(xv[n][p]), t0);
            t1 = fmaf(pr[n], h2hi(xv[n][p]), t1);
        }
        acc[2 * p]     = fmaf(acc[2 * p],     sc, t0);
        acc[2 * p + 1] = fmaf(acc[2 * p + 1], sc, t1);
    }
}

template <int D, int C, int CB, int WPN, bool RELU>
__global__ __launch_bounds__(256) void attn_hase(
    const unsigned short* __restrict__ xl, const unsigned short* __restrict__ xr,
    const uint4* __restrict__ ead4,
    const float* __restrict__ We, const float* __restrict__ att,
    const int* __restrict__ srcs, const int* __restrict__ off,
    const float* __restrict__ bias, unsigned short* __restrict__ outp, int N) {
    constexpr int CPL = CB / 64;
    constexpr int P = CPL / 2;
    constexpr int HW = CB / C;
    constexpr int G = 64 / HW;
    constexpr int NPB = 4 / WPN;
    // LDS We: linear channel-pair half2 per k: wsh[k*(D/2) + c/2] = (We[k][c], We[k][c+1])
    __shared__ unsigned wsh[4 * D];
    for (int idx = threadIdx.x; idx < 4 * D; idx += 256) {
        int k = idx / (D / 2);
        int r = idx - k * (D / 2);
        int c = 2 * r;
        wsh[idx] = ph2(We[(size_t)k * D + c], We[(size_t)k * D + c + 1]);
    }
    __syncthreads();

    const int wid = threadIdx.x >> 6, lane = threadIdx.x & 63;
    const int wv = wid % WPN, wn = wid / WPN;
    const int c0 = wv * CB + lane * CPL;
    const unsigned* wbu = wsh + wv * (CB / 2) + lane * (CPL / 2);

    const float L2E = 1.4426950408889634f;   // exp2-domain softmax
    half2t att2[P];
#pragma unroll
    for (int p = 0; p < P; ++p)
        att2[p] = mk_h2(att[c0 + 2 * p] * L2E, att[c0 + 2 * p + 1] * L2E);

    for (int node = blockIdx.x * NPB + wn; node < N; node += gridDim.x * NPB) {
        half2t xr2[P];
        loadh2<CPL>(xr + (size_t)node * D + c0, xr2);
        float m = -1e30f, l = 0.f, acc[CPL];
#pragma unroll
        for (int c = 0; c < CPL; ++c) acc[c] = 0.f;

        const int jb = __builtin_amdgcn_readfirstlane(off[node]);
        const int je = __builtin_amdgcn_readfirstlane(off[node + 1]);
        int j = jb;
        for (; j + 4 <= je; j += 4)
            hase_group<D, CPL, G, 4>(xl, ead4 + 2 * j, srcs + j, wbu, att2, xr2, c0, m, l, acc);
        for (; j < je; ++j)
            hase_group<D, CPL, G, 1>(xl, ead4 + 2 * j, srcs + j, wbu, att2, xr2, c0, m, l, acc);

        float inv = 1.f / (l + 1e-16f);
        float r[CPL];
#pragma unroll
        for (int c = 0; c < CPL; ++c) {
            r[c] = fmaf(acc[c], inv, bias[c0 + c]);
            if constexpr (RELU) r[c] = fmaxf(r[c], 0.f);
        }
        store_bf16v<CPL>(outp + (size_t)node * D + c0, r);
    }
}

// ---------- fused attention, no edge_attr (layer 3), packed f16 ----------
template <int D, int CPL, int G, int NE>
static __device__ __forceinline__ void noe_group(
    const unsigned short* __restrict__ xl, const int* __restrict__ sj,
    const half2t (&att2)[CPL / 2], const half2t (&xr2)[CPL / 2], int c0,
    float& m, float& l, float (&acc)[CPL]) {
    constexpr int P = CPL / 2;
    int src[NE];
#pragma unroll
    for (int n = 0; n < NE; ++n) src[n] = sj[n];
    half2t xv[NE][P];
#pragma unroll
    for (int n = 0; n < NE; ++n)
        loadh2<CPL>(xl + (size_t)src[n] * D + c0, xv[n]);
    const half2t c02 = mk_h2(0.2f, 0.2f);
    float lg[NE];
#pragma unroll
    for (int n = 0; n < NE; ++n) {
        float t = 0.f;
#pragma unroll
        for (int p = 0; p < P; ++p) {
            half2t zz = xv[n][p] + xr2[p];
            half2t lz = __builtin_elementwise_max(zz, zz * c02);
            t = fdot2h(att2[p], lz, t);
        }
        lg[n] = group_reduce<G>(t);
    }
    float mn = m;
#pragma unroll
    for (int n = 0; n < NE; ++n) mn = fmaxf(mn, lg[n]);
    float sc = fexp2(m - mn);
    float pr[NE], ps = 0.f;
#pragma unroll
    for (int n = 0; n < NE; ++n) { pr[n] = fexp2(lg[n] - mn); ps += pr[n]; }
    m = mn;
    l = fmaf(l, sc, ps);
#pragma unroll
    for (int p = 0; p < P; ++p) {
        float t0 = pr[0] * h2lo(xv[0][p]);
        float t1 = pr[0] * h2hi(xv[0][p]);
#pragma unroll
        for (int n = 1; n < NE; ++n) {
            t0 = fmaf(pr[n], h2lo(xv[n][p]), t0);
            t1 = fmaf(pr[n], h2hi(xv[n][p]), t1);
        }
        acc[2 * p]     = fmaf(acc[2 * p],     sc, t0);
        acc[2 * p + 1] = fmaf(acc[2 * p + 1], sc, t1);
    }
}

template <int D, int C, int CB, bool RELU>
static __device__ __forceinline__ void attn_wave3(
    const unsigned short* __restrict__ xl, const unsigned short* __restrict__ xr,
    const float* __restrict__ att,
    const int* __restrict__ srcs, int jb, int je,
    const float* __restrict__ bias, float* __restrict__ outp,
    int node, int cb, int lane) {
    constexpr int CPL = CB / 64;
    constexpr int P = CPL / 2;
    constexpr int HW = CB / C;
    constexpr int G = 64 / HW;
    const int c0 = cb + lane * CPL;
    const float L2E = 1.4426950408889634f;

    half2t xr2[P], att2[P];
    loadh2<CPL>(xr + (size_t)node * D + c0, xr2);
#pragma unroll
    for (int p = 0; p < P; ++p)
        att2[p] = mk_h2(att[c0 + 2 * p] * L2E, att[c0 + 2 * p + 1] * L2E);

    float m = -1e30f, l = 0.f, acc[CPL];
#pragma unroll
    for (int c = 0; c < CPL; ++c) acc[c] = 0.f;

    int j = jb;
    for (; j + 4 <= je; j += 4)
        noe_group<D, CPL, G, 4>(xl, srcs + j, att2, xr2, c0, m, l, acc);
    for (; j < je; ++j)
        noe_group<D, CPL, G, 1>(xl, srcs + j, att2, xr2, c0, m, l, acc);

    float inv = 1.f / (l + 1e-16f);
    float* out = outp + (size_t)node * D + c0;
    float tmp[CPL];
#pragma unroll
    for (int c = 0; c < CPL; ++c) {
        float r = fmaf(acc[c], inv, bias[c0 + c]);
        if constexpr (RELU) r = fmaxf(r, 0.f);
        tmp[c] = r;
    }
    if constexpr (CPL == 4) *(float4*)out = *(float4*)tmp;
    else if constexpr (CPL == 2) *(float2*)out = *(float2*)tmp;
    else out[0] = tmp[0];
}

template <int D, int C, int CB0, int CB1, bool RELU>
__global__ __launch_bounds__(256) void attn_noe(
    const unsigned short* __restrict__ xl, const unsigned short* __restrict__ xr,
    const float* __restrict__ att,
    const int* __restrict__ srcs, const int* __restrict__ off,
    const float* __restrict__ bias, float* __restrict__ outp, int N) {
    const int wid = threadIdx.x >> 6, lane = threadIdx.x & 63;
    const int gw = blockIdx.x * 4 + wid;
    const int node = gw >> 1, wv = gw & 1;
    if (node >= N) return;
    const int jb = __builtin_amdgcn_readfirstlane(off[node]);
    const int je = __builtin_amdgcn_readfirstlane(off[node + 1]);
    if (wv == 0)
        attn_wave3<D, C, CB0, RELU>(xl, xr, att, srcs, jb, je, bias, outp, node, 0, lane);
    else
        attn_wave3<D, C, CB1, RELU>(xl, xr, att, srcs, jb, je, bias, outp, node, CB0, lane);
}

// ---------- head: 2-layer MLP on master (last) node of each graph ----------
__global__ void mlp_kernel(const float* __restrict__ h3, const int* __restrict__ nn,
                           const float* __restrict__ Wfc1, const float* __restrict__ bfc1,
                           const float* __restrict__ Wfc2, const float* __restrict__ bfc2,
                           float* __restrict__ out, int G) {
    int g = blockIdx.x, t = threadIdx.x;  // 64 threads
    int s = 0;
    for (int k = 0; k <= g; ++k) s += nn[k];
    const float* row = h3 + (size_t)(s - 1) * 384;
    float z = bfc1[t];
    for (int k = 0; k < 384; ++k) z = fmaf(row[k], Wfc1[k * 64 + t], z);
    z = fmaxf(z, 0.f);
    float v = z * Wfc2[t];
#pragma unroll
    for (int o = 32; o; o >>= 1) v += __shfl_xor(v, o, 64);
    if (t == 0) out[g] = v + bfc2[0];
}

extern "C" void kernel_launch(void* const* d_in, const int* in_sizes, int n_in,
                              void* d_out, int out_size, void* d_ws, size_t ws_size,
                              hipStream_t stream) {
    const float* x    = (const float*)d_in[0];
    const float* ea   = (const float*)d_in[1];
    const float* Wl1  = (const float*)d_in[2];
    const float* Wr1  = (const float*)d_in[3];
    const float* We1  = (const float*)d_in[4];
    const float* att1 = (const float*)d_in[5];
    const float* b1   = (const float*)d_in[6];
    const float* Wl2  = (const float*)d_in[7];
    const float* Wr2  = (const float*)d_in[8];
    const float* We2  = (const float*)d_in[9];
    const float* att2 = (const float*)d_in[10];
    const float* b2   = (const float*)d_in[11];
    const float* Wlp  = (const float*)d_in[12];
    const float* Wrp  = (const float*)d_in[13];
    const float* attp = (const float*)d_in[14];
    const float* bp   = (const float*)d_in[15];
    const float* Wfc1 = (const float*)d_in[16];
    const float* bfc1 = (const float*)d_in[17];
    const float* Wfc2 = (const float*)d_in[18];
    const float* bfc2 = (const float*)d_in[19];
    const int* ei     = (const int*)d_in[20];
    const int* eim    = (const int*)d_in[21];
    const int* nn     = (const int*)d_in[22];

    const int N = in_sizes[0] / 64;   // 20000
    const int E = in_sizes[20] / 2;   // 160000
    const int G = in_sizes[22];       // 100
    const int* src1 = ei,  *dst1 = ei + E;
    const int* srcm = eim, *dstm = eim + E;

    // ---- workspace layout (unchanged footprint) ----
    char* w = (char*)d_ws;
    size_t o = 0;
    auto alloc = [&](size_t b) { size_t r = o; o += (b + 255) & ~(size_t)255; return r; };
    char* R1 = w + alloc((size_t)N * 2048 * 2);
    unsigned short* xl1 = (unsigned short*)R1;
    unsigned short* xr1 = xl1 + (size_t)N * 1024;
    unsigned short* xl3 = (unsigned short*)R1;
    unsigned short* xr3 = xl3 + (size_t)N * 384;
    float* h3 = (float*)(R1 + (size_t)N * 768 * 2 + 256);
    unsigned short* h1   = (unsigned short*)(w + alloc((size_t)N * 1024 * 2));
    char* R2 = w + alloc((size_t)N * 512 * 2);
    unsigned short* xl2 = (unsigned short*)R2;
    unsigned short* xr2 = xl2 + (size_t)N * 256;
    unsigned short* h2   = (unsigned short*)(w + alloc((size_t)N * 256 * 2));
    unsigned short* xbf  = (unsigned short*)(w + alloc((size_t)N * 64 * 2));
    unsigned short* wt1  = (unsigned short*)(w + alloc((size_t)2048 * 64 * 2));
    unsigned short* wt2  = (unsigned short*)(w + alloc((size_t)512 * 1024 * 2));
    unsigned short* wt3  = (unsigned short*)(w + alloc((size_t)768 * 256 * 2));
    int*  cnt   = (int*)(w + alloc((size_t)2 * N * 4));
    int*  off   = (int*)(w + alloc((size_t)2 * (N + 1) * 4));
    int*  cur   = (int*)(w + alloc((size_t)2 * N * 4));
    char* eReg  = w + alloc((size_t)2 * E * 8 + 4096);
    int2* edges = (int2*)eReg;
    int*  srcs  = (int*)(eReg + (size_t)E * 8);
    (void)ws_size; (void)n_in; (void)out_size;

    // dead-region reuse (zero extra footprint):
    uint4* ead1 = (uint4*)R2;     // E*32 B = 10.24 MB <= 20.48 MB, dead until gemm2
    uint4* ead2 = (uint4*)h1;     // 10.24 MB <= 40.96 MB, dead after gemm2 consumed h1

    dim3 blk(256);

    // ---- weight prep (single merged launch) ----
    {
        int tot = 2 * 64 * 1024 + 2 * 1024 * 256 + 2 * 256 * 384 + N * 64;
        prep_all<<<DIV_UP(tot, 256), blk, 0, stream>>>(x, Wl1, Wr1, Wl2, Wr2, Wlp, Wrp,
                                                       xbf, wt1, wt2, wt3, N);
    }

    // ---- CSR for both graphs ----
    hipMemsetAsync(cnt, 0, (size_t)2 * N * 4, stream);
    count2_kernel<<<DIV_UP(2 * E, 256), blk, 0, stream>>>(dst1, dstm, E, N, cnt);
    scan_kernel<<<2, 1024, 0, stream>>>(cnt, N, off, cur);
    fill2_kernel<<<DIV_UP(2 * E, 256), blk, 0, stream>>>(src1, dst1, srcm, dstm, E, N, cur,
                                                         edges, srcs);
    ea_gather_kernel<<<DIV_UP(E, 256), blk, 0, stream>>>(ea, edges, ead1, E);
    const int* off3 = off + (N + 1);
    const int* srcs3 = srcs + E;

    // ---- Layer 1: H=4, C=256, D=1024 — 2 waves/node, CPL=8, G=32 ----
    gemm_mfma<<<dim3(2048 / 128, DIV_UP(N, 128)), blk, 0, stream>>>(
        xbf, wt1, xl1, xr1, N, 1024, 64);
    attn_hase<1024, 256, 512, 2, true><<<2560, blk, 0, stream>>>(
        xl1, xr1, ead1, We1, att1, srcs, off, b1, h1, N);

    // ---- Layer 2: H=4, C=64, D=256 — 1 wave/node, CPL=4, G=16 ----
    gemm_mfma<<<dim3(512 / 128, DIV_UP(N, 128)), blk, 0, stream>>>(
        h1, wt2, xl2, xr2, N, 256, 1024);
    ea_gather_kernel<<<DIV_UP(E, 256), blk, 0, stream>>>(ea, edges, ead2, E);
    attn_hase<256, 64, 256, 1, true><<<1280, blk, 0, stream>>>(
        xl2, xr2, ead2, We2, att2, srcs, off, b2, h2, N);

    // ---- Layer 3: H=6, C=64, D=384 — 2 waves/node (roles 256/128), fp32 out ----
    gemm_mfma<<<dim3(768 / 128, DIV_UP(N, 128)), blk, 0, stream>>>(
        h2, wt3, xl3, xr3, N, 384, 256);
    attn_noe<384, 64, 256, 128, false><<<DIV_UP(N, 2), blk, 0, stream>>>(
        xl3, xr3, attp, srcs3, off3, bp, h3, N);

    // ---- head ----
    mlp_kernel<<<G, 64, 0, stream>>>(h3, nn, Wfc1, bfc1, Wfc2, bfc2, (float*)d_out, G);
}